// Round 1
// baseline (1054.091 us; speedup 1.0000x reference)
//
#include <hip/hip_runtime.h>
#include <hip/hip_bf16.h>

// Problem constants (B,T,D,H) = (64, 32, 256, 4); DIMS = [1024, 512, 256, 128, 64, 4]
// Outputs (flat, f32): camera_corr[64] | rot_res[64*4] | trans_res[64*3]
//                      | plane_corr[64*32*32] | valid[64*32*32]
// out_size = 64 + 256 + 192 + 65536 + 65536 = 131584

constexpr int O_CAM   = 0;
constexpr int O_ROT   = 64;
constexpr int O_TRANS = 320;
constexpr int O_PLANE = 512;
constexpr int O_VALID = 66048;

// Workspace layout (floats)
constexpr size_t OFF_G1  = 0;           // 64*256
constexpr size_t OFF_G2  = 16384;       // 64*256
constexpr size_t OFF_G   = 32768;       // 4*64*512
constexpr size_t OFF_ACC = 163840;      // 64*8 (cam, rot[4], trans[3])
constexpr size_t OFF_A   = 164352;      // 4*64*32*512
constexpr size_t OFF_C   = 4358656;     // 4*64*32*512
// total = 8552960 floats = 34.2 MB

__device__ __forceinline__ float sigmoidf_(float x) {
    return 1.f / (1.f + __expf(-x) * 0.f + expf(-x) * 1.f); // keep libm expf for accuracy
}

// ---------------- K1: group means g1, g2 ----------------
__global__ __launch_bounds__(256) void k_groups(
    const float* __restrict__ emb, const int* __restrict__ np_,
    float* __restrict__ g1, float* __restrict__ g2)
{
    const int b = blockIdx.x, d = threadIdx.x;
    const int n0 = np_[2*b], n1 = np_[2*b+1];
    const float* e = emb + (size_t)b*32*256 + d;
    float a1 = 0.f, a2 = 0.f;
    for (int t = 0; t < 32; ++t) {
        float v = e[(size_t)t*256];
        if (t < n0) a1 += v;
        else if (t < n0 + n1) a2 += v;
    }
    g1[b*256 + d] = a1 / n0;
    g2[b*256 + d] = a2 / n1;
}

// ---------------- K2: A and C partial layer-0 GEMMs ----------------
// grid: (2 col-halves, B, H*2) ; z = h*2 + isC
__global__ __launch_bounds__(256) void k_AC(
    const float* __restrict__ emb, const float* __restrict__ w0,
    float* __restrict__ Abuf, float* __restrict__ Cbuf)
{
    const int half = blockIdx.x, b = blockIdx.y;
    const int h = blockIdx.z >> 1, isC = blockIdx.z & 1;
    const int tid = threadIdx.x;

    __shared__ __align__(16) float es[32][256];   // 32 KB
    for (int i = tid; i < 32*256; i += 256)
        es[i >> 8][i & 255] = emb[(size_t)b*32*256 + i];
    __syncthreads();

    const int k = half*256 + tid;
    const float* w = w0 + (size_t)h*(1024*512) + (size_t)(isC ? 256 : 0)*512 + k;

    float acc[32];
    #pragma unroll
    for (int t = 0; t < 32; ++t) acc[t] = 0.f;

    for (int d = 0; d < 256; d += 4) {
        const float wv0 = w[(size_t)(d+0)*512];
        const float wv1 = w[(size_t)(d+1)*512];
        const float wv2 = w[(size_t)(d+2)*512];
        const float wv3 = w[(size_t)(d+3)*512];
        #pragma unroll
        for (int t = 0; t < 32; ++t) {
            const float4 ev = *(const float4*)(&es[t][d]);
            float a = acc[t];
            a = fmaf(ev.x, wv0, a);
            a = fmaf(ev.y, wv1, a);
            a = fmaf(ev.z, wv2, a);
            a = fmaf(ev.w, wv3, a);
            acc[t] = a;
        }
    }

    float* dst = (isC ? Cbuf : Abuf) + ((size_t)(h*64 + b)*32)*512 + k;
    for (int t = 0; t < 32; ++t) dst[(size_t)t*512] = acc[t];
}

// ---------------- K3: G = g1*W0c + g2*W0d + b0 ----------------
// grid: (2, B, H)
__global__ __launch_bounds__(256) void k_G(
    const float* __restrict__ g1, const float* __restrict__ g2,
    const float* __restrict__ w0, const float* __restrict__ b0,
    float* __restrict__ Gbuf)
{
    const int half = blockIdx.x, b = blockIdx.y, h = blockIdx.z;
    const int tid = threadIdx.x;
    __shared__ float s1[256], s2[256];
    s1[tid] = g1[b*256 + tid];
    s2[tid] = g2[b*256 + tid];
    __syncthreads();

    const int k = half*256 + tid;
    const float* wA = w0 + (size_t)h*(1024*512) + (size_t)512*512 + k;
    const float* wB = wA + (size_t)256*512;
    float a = b0[h*512 + k];
    for (int d = 0; d < 256; ++d) {
        a = fmaf(s1[d], wA[(size_t)d*512], a);
        a = fmaf(s2[d], wB[(size_t)d*512], a);
    }
    Gbuf[(size_t)(h*64 + b)*512 + k] = a;
}

// ---------------- K4: fused per-(b, t, s-half, h) MLP ----------------
// grid: (T*2, B, H), block 256. Rows = 16 s-positions for fixed t.
__global__ __launch_bounds__(256) void k_main(
    const float* __restrict__ Abuf, const float* __restrict__ Cbuf,
    const float* __restrict__ Gbuf,
    const float* __restrict__ w1, const float* __restrict__ b1,
    const float* __restrict__ w2, const float* __restrict__ b2,
    const float* __restrict__ w3, const float* __restrict__ b3,
    const float* __restrict__ w4, const float* __restrict__ b4,
    const int* __restrict__ np_, float* __restrict__ out, float* __restrict__ acc)
{
    const int t  = blockIdx.x >> 1;
    const int s0 = (blockIdx.x & 1) * 16;
    const int b  = blockIdx.y;
    const int h  = blockIdx.z;
    const int tid = threadIdx.x;

    const int n0 = np_[2*b], n1 = np_[2*b+1];
    if (h < 3) {
        // heads 0..2 feed only masked sums: t < n0, s in [n0, n0+n1)
        if (t >= n0) return;
        if (s0 >= n0 + n1 || s0 + 16 <= n0) return;
    }

    __shared__ __align__(16) float AG[512];        // 2 KB
    __shared__ __align__(16) float X0[16][512];    // 32 KB
    __shared__ __align__(16) float X1[16][256];    // 16 KB

    const size_t hb = (size_t)(h*64 + b);

    // AG[k] = A[h,b,t,k] + G[h,b,k]
    {
        const float* Ar = Abuf + (hb*32 + t)*512;
        const float* Gr = Gbuf + hb*512;
        AG[tid]       = Ar[tid]       + Gr[tid];
        AG[tid + 256] = Ar[tid + 256] + Gr[tid + 256];
    }
    __syncthreads();

    // X0[s][k] = relu(AG[k] + C[h,b,s0+s,k])
    {
        const float* Cr = Cbuf + (hb*32 + s0)*512;
        #pragma unroll
        for (int i = 0; i < 32; ++i) {
            const int idx = i*256 + tid;
            const int s = idx >> 9, k = idx & 511;
            const float v = AG[k] + Cr[(size_t)s*512 + k];
            X0[s][k] = fmaxf(v, 0.f);
        }
    }
    __syncthreads();

    // layer1: 512 -> 256 (each thread owns one output column)
    {
        const float* w = w1 + (size_t)h*(512*256) + tid;
        float a[16];
        #pragma unroll
        for (int s = 0; s < 16; ++s) a[s] = 0.f;
        for (int d = 0; d < 512; d += 4) {
            const float wv0 = w[(size_t)(d+0)*256];
            const float wv1 = w[(size_t)(d+1)*256];
            const float wv2 = w[(size_t)(d+2)*256];
            const float wv3 = w[(size_t)(d+3)*256];
            #pragma unroll
            for (int s = 0; s < 16; ++s) {
                const float4 x = *(const float4*)(&X0[s][d]);
                float av = a[s];
                av = fmaf(x.x, wv0, av);
                av = fmaf(x.y, wv1, av);
                av = fmaf(x.z, wv2, av);
                av = fmaf(x.w, wv3, av);
                a[s] = av;
            }
        }
        const float bb = b1[h*256 + tid];
        #pragma unroll
        for (int s = 0; s < 16; ++s) X1[s][tid] = fmaxf(a[s] + bb, 0.f);
    }
    __syncthreads();

    // layer2: 256 -> 128 (X2 overlays X0; X0 dead after the sync above)
    float (*X2)[128] = (float(*)[128])(&X0[0][0]);
    {
        const int k = tid & 127, sg = tid >> 7;    // 2 groups x 8 rows
        const float* w = w2 + (size_t)h*(256*128) + k;
        float a[8];
        #pragma unroll
        for (int i = 0; i < 8; ++i) a[i] = 0.f;
        for (int d = 0; d < 256; d += 4) {
            const float wv0 = w[(size_t)(d+0)*128];
            const float wv1 = w[(size_t)(d+1)*128];
            const float wv2 = w[(size_t)(d+2)*128];
            const float wv3 = w[(size_t)(d+3)*128];
            #pragma unroll
            for (int i = 0; i < 8; ++i) {
                const float4 x = *(const float4*)(&X1[sg*8 + i][d]);
                float av = a[i];
                av = fmaf(x.x, wv0, av);
                av = fmaf(x.y, wv1, av);
                av = fmaf(x.z, wv2, av);
                av = fmaf(x.w, wv3, av);
                a[i] = av;
            }
        }
        const float bb = b2[h*128 + k];
        #pragma unroll
        for (int i = 0; i < 8; ++i) X2[sg*8 + i][k] = fmaxf(a[i] + bb, 0.f);
    }
    __syncthreads();

    // layer3: 128 -> 64 (X3 overlays X1)
    float (*X3)[64] = (float(*)[64])(&X1[0][0]);
    {
        const int k = tid & 63, sg = tid >> 6;     // 4 groups x 4 rows
        const float* w = w3 + (size_t)h*(128*64) + k;
        float a[4];
        #pragma unroll
        for (int i = 0; i < 4; ++i) a[i] = 0.f;
        for (int d = 0; d < 128; d += 4) {
            const float wv0 = w[(size_t)(d+0)*64];
            const float wv1 = w[(size_t)(d+1)*64];
            const float wv2 = w[(size_t)(d+2)*64];
            const float wv3 = w[(size_t)(d+3)*64];
            #pragma unroll
            for (int i = 0; i < 4; ++i) {
                const float4 x = *(const float4*)(&X2[sg*4 + i][d]);
                float av = a[i];
                av = fmaf(x.x, wv0, av);
                av = fmaf(x.y, wv1, av);
                av = fmaf(x.z, wv2, av);
                av = fmaf(x.w, wv3, av);
                a[i] = av;
            }
        }
        const float bb = b3[h*64 + k];
        #pragma unroll
        for (int i = 0; i < 4; ++i) X3[sg*4 + i][k] = fmaxf(a[i] + bb, 0.f);
    }
    __syncthreads();

    // layer4: 64 -> 4 (X4 overlays AG; AG dead after X0 build)
    float (*X4)[4] = (float(*)[4])(&AG[0]);
    if (tid < 64) {
        const int s = tid >> 2, o = tid & 3;
        const float* w = w4 + (size_t)h*(64*4) + o;
        float a = b4[h*4 + o];
        for (int d = 0; d < 64; ++d) a = fmaf(X3[s][d], w[(size_t)d*4], a);
        X4[s][o] = a;
    }
    __syncthreads();

    // outputs
    if (h == 3) {
        if (tid < 16) {
            const float v = X4[tid][0];
            out[O_PLANE + b*1024 + t*32 + s0 + tid] = 1.f / (1.f + expf(-v));
        }
    } else if (h == 0) {
        if (tid < 16) {
            const int s = s0 + tid;
            float v = (s >= n0 && s < n0 + n1) ? X4[tid][0] : 0.f;
            #pragma unroll
            for (int off = 8; off > 0; off >>= 1) v += __shfl_down(v, off, 16);
            if (tid == 0) atomicAdd(&acc[b*8 + 0], v);
        }
    } else {
        const int nj = (h == 1) ? 4 : 3;
        if (tid < 16*nj) {
            const int j = tid >> 4, si = tid & 15;
            const int s = s0 + si;
            float v = (s >= n0 && s < n0 + n1) ? X4[si][j] : 0.f;
            #pragma unroll
            for (int off = 8; off > 0; off >>= 1) v += __shfl_down(v, off, 16);
            if (si == 0) atomicAdd(&acc[b*8 + (h == 1 ? 1 + j : 5 + j)], v);
        }
    }
}

// ---------------- K5: valid mask + finalize reductions ----------------
__global__ __launch_bounds__(1024) void k_final(
    const int* __restrict__ np_, const float* __restrict__ acc, float* __restrict__ out)
{
    const int b = blockIdx.x, tid = threadIdx.x;
    const int n0 = np_[2*b], n1 = np_[2*b+1];
    const int t = tid >> 5, s = tid & 31;
    out[O_VALID + b*1024 + tid] = (t < n0 && s >= n0 && s < n0 + n1) ? 1.f : 0.f;
    const float pf = (float)(n0 * n1);
    if (tid == 0) {
        out[O_CAM + b] = 1.f / (1.f + expf(-acc[b*8] / pf));
    } else if (tid <= 4) {
        out[O_ROT + b*4 + (tid - 1)] = acc[b*8 + tid] / pf;
    } else if (tid <= 7) {
        out[O_TRANS + b*3 + (tid - 5)] = acc[b*8 + tid] / pf;
    }
}

extern "C" void kernel_launch(void* const* d_in, const int* in_sizes, int n_in,
                              void* d_out, int out_size, void* d_ws, size_t ws_size,
                              hipStream_t stream) {
    (void)in_sizes; (void)n_in; (void)out_size; (void)ws_size;
    const float* emb = (const float*)d_in[0];
    const int*   np_ = (const int*)d_in[1];
    const float* w0  = (const float*)d_in[2];
    const float* b0  = (const float*)d_in[3];
    const float* w1  = (const float*)d_in[4];
    const float* b1  = (const float*)d_in[5];
    const float* w2  = (const float*)d_in[6];
    const float* b2  = (const float*)d_in[7];
    const float* w3  = (const float*)d_in[8];
    const float* b3  = (const float*)d_in[9];
    const float* w4  = (const float*)d_in[10];
    const float* b4  = (const float*)d_in[11];

    float* ws  = (float*)d_ws;
    float* out = (float*)d_out;

    hipMemsetAsync(ws + OFF_ACC, 0, 512 * sizeof(float), stream);

    k_groups<<<64, 256, 0, stream>>>(emb, np_, ws + OFF_G1, ws + OFF_G2);
    k_AC<<<dim3(2, 64, 8), 256, 0, stream>>>(emb, w0, ws + OFF_A, ws + OFF_C);
    k_G<<<dim3(2, 64, 4), 256, 0, stream>>>(ws + OFF_G1, ws + OFF_G2, w0, b0, ws + OFF_G);
    k_main<<<dim3(64, 64, 4), 256, 0, stream>>>(
        ws + OFF_A, ws + OFF_C, ws + OFF_G,
        w1, b1, w2, b2, w3, b3, w4, b4, np_, out, ws + OFF_ACC);
    k_final<<<64, 1024, 0, stream>>>(np_, ws + OFF_ACC, out);
}

// Round 2
// 274.507 us; speedup vs baseline: 3.8399x; 3.8399x over previous
//
#include <hip/hip_runtime.h>

typedef float f32x4 __attribute__((ext_vector_type(4)));
typedef short short8 __attribute__((ext_vector_type(8)));
typedef unsigned short ushort_t;
typedef unsigned int uint_t;

// Problem constants (B,T,D,H) = (64, 32, 256, 4); DIMS = [1024, 512, 256, 128, 64, 4]
constexpr int O_CAM   = 0;
constexpr int O_ROT   = 64;
constexpr int O_TRANS = 320;
constexpr int O_PLANE = 512;
constexpr int O_VALID = 66048;

// Workspace layout (float offsets)
constexpr size_t OFF_G1  = 0;           // 64*256
constexpr size_t OFF_G2  = 16384;       // 64*256
constexpr size_t OFF_G   = 32768;       // 4*64*512
constexpr size_t OFF_ACC = 163840;      // 64*8
constexpr size_t OFF_A   = 164352;      // 4*64*32*512
constexpr size_t OFF_C   = 4358656;     // 4*64*32*512
constexpr size_t OFF_BT  = 8552960;     // bf16 fragment-linear weights (ushort units from here)
// BT1 [4][16][16][64][8] = 1048576 ushorts; BT2 [4][8][8][64][8] = 131072; BT3 [4][4][4][64][8] = 32768
constexpr size_t BT2_OFF = 1048576;
constexpr size_t BT3_OFF = 1179648;

__device__ __forceinline__ ushort_t f2bf(float f) {
    uint_t u = __float_as_uint(f);
    return (ushort_t)((u + 0x7FFFu + ((u >> 16) & 1u)) >> 16);
}

// ---------------- K1: group means g1, g2 ----------------
__global__ __launch_bounds__(256) void k_groups(
    const float* __restrict__ emb, const int* __restrict__ np_,
    float* __restrict__ g1, float* __restrict__ g2)
{
    const int b = blockIdx.x, d = threadIdx.x;
    const int n0 = np_[2*b], n1 = np_[2*b+1];
    const float* e = emb + (size_t)b*32*256 + d;
    float a1 = 0.f, a2 = 0.f;
    for (int t = 0; t < 32; ++t) {
        float v = e[(size_t)t*256];
        if (t < n0) a1 += v;
        else if (t < n0 + n1) a2 += v;
    }
    g1[b*256 + d] = a1 / n0;
    g2[b*256 + d] = a2 / n1;
}

// ---------------- K2: A and C partial layer-0 GEMMs (fp32) ----------------
__global__ __launch_bounds__(256) void k_AC(
    const float* __restrict__ emb, const float* __restrict__ w0,
    float* __restrict__ Abuf, float* __restrict__ Cbuf)
{
    const int half = blockIdx.x, b = blockIdx.y;
    const int h = blockIdx.z >> 1, isC = blockIdx.z & 1;
    const int tid = threadIdx.x;

    __shared__ __align__(16) float es[32][256];
    for (int i = tid; i < 32*256; i += 256)
        es[i >> 8][i & 255] = emb[(size_t)b*32*256 + i];
    __syncthreads();

    const int k = half*256 + tid;
    const float* w = w0 + (size_t)h*(1024*512) + (size_t)(isC ? 256 : 0)*512 + k;

    float acc[32];
    #pragma unroll
    for (int t = 0; t < 32; ++t) acc[t] = 0.f;

    for (int d = 0; d < 256; d += 4) {
        const float wv0 = w[(size_t)(d+0)*512];
        const float wv1 = w[(size_t)(d+1)*512];
        const float wv2 = w[(size_t)(d+2)*512];
        const float wv3 = w[(size_t)(d+3)*512];
        #pragma unroll
        for (int t = 0; t < 32; ++t) {
            const float4 ev = *(const float4*)(&es[t][d]);
            float a = acc[t];
            a = fmaf(ev.x, wv0, a);
            a = fmaf(ev.y, wv1, a);
            a = fmaf(ev.z, wv2, a);
            a = fmaf(ev.w, wv3, a);
            acc[t] = a;
        }
    }

    float* dst = (isC ? Cbuf : Abuf) + ((size_t)(h*64 + b)*32)*512 + k;
    for (int t = 0; t < 32; ++t) dst[(size_t)t*512] = acc[t];
}

// ---------------- K3: G = g1*W0c + g2*W0d + b0 ----------------
__global__ __launch_bounds__(256) void k_G(
    const float* __restrict__ g1, const float* __restrict__ g2,
    const float* __restrict__ w0, const float* __restrict__ b0,
    float* __restrict__ Gbuf)
{
    const int half = blockIdx.x, b = blockIdx.y, h = blockIdx.z;
    const int tid = threadIdx.x;
    __shared__ float s1[256], s2[256];
    s1[tid] = g1[b*256 + tid];
    s2[tid] = g2[b*256 + tid];
    __syncthreads();

    const int k = half*256 + tid;
    const float* wA = w0 + (size_t)h*(1024*512) + (size_t)512*512 + k;
    const float* wB = wA + (size_t)256*512;
    float a = b0[h*512 + k];
    for (int d = 0; d < 256; ++d) {
        a = fmaf(s1[d], wA[(size_t)d*512], a);
        a = fmaf(s2[d], wB[(size_t)d*512], a);
    }
    Gbuf[(size_t)(h*64 + b)*512 + k] = a;
}

// ---------------- K-prep: fragment-linear bf16 weights ----------------
// Fragment layout: lane l, elem j: value = W[h][d = ks*32 + (l>>4)*8 + j][n = nt*16 + (l&15)]
__global__ __launch_bounds__(64) void k_wprep(
    const float* __restrict__ w1, const float* __restrict__ w2, const float* __restrict__ w3,
    ushort_t* __restrict__ bt)
{
    int c = blockIdx.x;
    const float* w; ushort_t* dst; int K, N, NT;
    if (c < 1024)      { w = w1; dst = bt;           K = 512; N = 256; NT = 16; }
    else if (c < 1280) { c -= 1024; w = w2; dst = bt + BT2_OFF; K = 256; N = 128; NT = 8; }
    else               { c -= 1280; w = w3; dst = bt + BT3_OFF; K = 128; N = 64;  NT = 4; }
    const int KS_NT = (K/32)*NT;
    const int h = c / KS_NT, rem = c % KS_NT, ks = rem / NT, nt = rem % NT;
    const int l = threadIdx.x;
    const int n = nt*16 + (l & 15);
    const int d0 = ks*32 + ((l >> 4) << 3);
    short8 o;
    #pragma unroll
    for (int j = 0; j < 8; ++j) {
        float v = w[((size_t)(h*K + d0 + j))*N + n];
        o[j] = (short)f2bf(v);
    }
    *(short8*)(dst + ((size_t)c*64 + l)*8) = o;
}

// ---------------- K4: fused MFMA MLP per (t, b, h) ----------------
__global__ __launch_bounds__(256) void k_main(
    const float* __restrict__ Abuf, const float* __restrict__ Cbuf, const float* __restrict__ Gbuf,
    const ushort_t* __restrict__ bt,
    const float* __restrict__ b1, const float* __restrict__ b2, const float* __restrict__ b3,
    const float* __restrict__ w4, const float* __restrict__ b4,
    const int* __restrict__ np_, float* __restrict__ out, float* __restrict__ accbuf)
{
    const int t = blockIdx.x, b = blockIdx.y, h = blockIdx.z;
    const int n0 = np_[2*b], n1 = np_[2*b+1];
    if (h < 3 && t >= n0) return;   // heads 0..2 only feed masked sums over t < n0

    __shared__ __align__(16) char smem[49152];
    const int tid = threadIdx.x;
    const int l = tid & 63, w = tid >> 6;
    const int lrow = l & 15, lko = l >> 4;
    const size_t hb = (size_t)(h*64 + b);

    // ---- build X0 = relu(A_t + G + C_s) as bf16 [32][512], rowstride 1024B, swizzled ----
    {
        const float2 Ar = *(const float2*)(Abuf + (hb*32 + t)*512 + 2*tid);
        const float2 Gr = *(const float2*)(Gbuf + hb*512 + 2*tid);
        const float ag0 = Ar.x + Gr.x, ag1 = Ar.y + Gr.y;
        const float* Cb = Cbuf + (hb*32)*512 + 2*tid;
        for (int s = 0; s < 32; ++s) {
            const float2 c = *(const float2*)(Cb + (size_t)s*512);
            const uint_t p = (uint_t)f2bf(fmaxf(ag0 + c.x, 0.f))
                           | ((uint_t)f2bf(fmaxf(ag1 + c.y, 0.f)) << 16);
            int byte = s*1024 + tid*4;
            byte ^= ((s & 7) << 4);
            *(uint_t*)(smem + byte) = p;
        }
    }
    __syncthreads();

    // ---- layer1: [32 x 512] x [512 x 256] -> X1 bf16 [32][256] ----
    f32x4 acc1[2][4];
    #pragma unroll
    for (int mt = 0; mt < 2; ++mt)
        #pragma unroll
        for (int nt = 0; nt < 4; ++nt) acc1[mt][nt] = (f32x4){0.f,0.f,0.f,0.f};
    {
        const ushort_t* bt1 = bt + (size_t)h*16*16*512;
        const int kb = lko*16;
        for (int ks = 0; ks < 16; ++ks) {
            const int o0 = ((lrow)*1024     + ks*64 + kb) ^ ((lrow & 7) << 4);
            const int o1 = ((16+lrow)*1024  + ks*64 + kb) ^ ((lrow & 7) << 4);
            const short8 a0 = *(const short8*)(smem + o0);
            const short8 a1 = *(const short8*)(smem + o1);
            #pragma unroll
            for (int nt = 0; nt < 4; ++nt) {
                const int ntg = w*4 + nt;
                const short8 bf = *(const short8*)(bt1 + ((size_t)(ks*16 + ntg)*64 + l)*8);
                acc1[0][nt] = __builtin_amdgcn_mfma_f32_16x16x32_bf16(a0, bf, acc1[0][nt], 0, 0, 0);
                acc1[1][nt] = __builtin_amdgcn_mfma_f32_16x16x32_bf16(a1, bf, acc1[1][nt], 0, 0, 0);
            }
        }
    }
    char* X1 = smem + 32768;     // bf16 [32][256], rowstride 512B, swizzled
    #pragma unroll
    for (int nt = 0; nt < 4; ++nt) {
        const int col = w*64 + nt*16 + lrow;
        const float bias = b1[h*256 + col];
        #pragma unroll
        for (int mt = 0; mt < 2; ++mt)
            #pragma unroll
            for (int r = 0; r < 4; ++r) {
                const int row = mt*16 + lko*4 + r;
                const float v = fmaxf(acc1[mt][nt][r] + bias, 0.f);
                int byte = row*512 + col*2;
                byte ^= ((row & 7) << 4);
                *(ushort_t*)(X1 + byte) = f2bf(v);
            }
    }
    __syncthreads();

    // ---- layer2: [32 x 256] x [256 x 128] -> X2 bf16 [32][128] (overlays X0) ----
    f32x4 acc2[2][2];
    #pragma unroll
    for (int mt = 0; mt < 2; ++mt)
        #pragma unroll
        for (int nt = 0; nt < 2; ++nt) acc2[mt][nt] = (f32x4){0.f,0.f,0.f,0.f};
    {
        const ushort_t* bt2 = bt + BT2_OFF + (size_t)h*8*8*512;
        const int kb = lko*16;
        for (int ks = 0; ks < 8; ++ks) {
            const int o0 = ((lrow)*512    + ks*64 + kb) ^ ((lrow & 7) << 4);
            const int o1 = ((16+lrow)*512 + ks*64 + kb) ^ ((lrow & 7) << 4);
            const short8 a0 = *(const short8*)(X1 + o0);
            const short8 a1 = *(const short8*)(X1 + o1);
            #pragma unroll
            for (int nt = 0; nt < 2; ++nt) {
                const int ntg = w*2 + nt;
                const short8 bf = *(const short8*)(bt2 + ((size_t)(ks*8 + ntg)*64 + l)*8);
                acc2[0][nt] = __builtin_amdgcn_mfma_f32_16x16x32_bf16(a0, bf, acc2[0][nt], 0, 0, 0);
                acc2[1][nt] = __builtin_amdgcn_mfma_f32_16x16x32_bf16(a1, bf, acc2[1][nt], 0, 0, 0);
            }
        }
    }
    char* X2 = smem;             // bf16 [32][128], rowstride 256B, swizzled
    #pragma unroll
    for (int nt = 0; nt < 2; ++nt) {
        const int col = w*32 + nt*16 + lrow;
        const float bias = b2[h*128 + col];
        #pragma unroll
        for (int mt = 0; mt < 2; ++mt)
            #pragma unroll
            for (int r = 0; r < 4; ++r) {
                const int row = mt*16 + lko*4 + r;
                const float v = fmaxf(acc2[mt][nt][r] + bias, 0.f);
                int byte = row*256 + col*2;
                byte ^= ((row & 7) << 4);
                *(ushort_t*)(X2 + byte) = f2bf(v);
            }
    }
    __syncthreads();

    // ---- layer3: [32 x 128] x [128 x 64] -> X3 f32 [32][64] ----
    f32x4 acc3[2];
    acc3[0] = (f32x4){0.f,0.f,0.f,0.f};
    acc3[1] = (f32x4){0.f,0.f,0.f,0.f};
    {
        const ushort_t* bt3 = bt + BT3_OFF + (size_t)h*4*4*512;
        const int kb = lko*16;
        for (int ks = 0; ks < 4; ++ks) {
            const int o0 = ((lrow)*256    + ks*64 + kb) ^ ((lrow & 7) << 4);
            const int o1 = ((16+lrow)*256 + ks*64 + kb) ^ ((lrow & 7) << 4);
            const short8 a0 = *(const short8*)(X2 + o0);
            const short8 a1 = *(const short8*)(X2 + o1);
            const short8 bf = *(const short8*)(bt3 + ((size_t)(ks*4 + w)*64 + l)*8);
            acc3[0] = __builtin_amdgcn_mfma_f32_16x16x32_bf16(a0, bf, acc3[0], 0, 0, 0);
            acc3[1] = __builtin_amdgcn_mfma_f32_16x16x32_bf16(a1, bf, acc3[1], 0, 0, 0);
        }
    }
    float* X3 = (float*)(smem + 8192);   // f32 [32][64], plain
    {
        const int col = w*16 + lrow;
        const float bias = b3[h*64 + col];
        #pragma unroll
        for (int mt = 0; mt < 2; ++mt)
            #pragma unroll
            for (int r = 0; r < 4; ++r) {
                const int row = mt*16 + lko*4 + r;
                X3[row*64 + col] = fmaxf(acc3[mt][r] + bias, 0.f);
            }
    }
    __syncthreads();

    // ---- layer4: [32 x 64] x [64 x 4] (VALU) ----
    float* X4 = (float*)(smem + 32768);  // f32 [32][4]
    if (tid < 128) {
        const int s = tid >> 2, o = tid & 3;
        const float* wr = w4 + (size_t)h*256 + o;
        float a = b4[h*4 + o];
        const float* xr = X3 + s*64;
        #pragma unroll
        for (int d = 0; d < 64; ++d) a = fmaf(xr[d], wr[(size_t)d*4], a);
        X4[s*4 + o] = a;
    }
    __syncthreads();

    // ---- outputs ----
    if (h == 3) {
        if (tid < 32)
            out[O_PLANE + b*1024 + t*32 + tid] = 1.f / (1.f + expf(-X4[tid*4]));
    } else if (h == 0) {
        if (tid < 32) {
            float v = (tid >= n0 && tid < n0 + n1) ? X4[tid*4] : 0.f;
            #pragma unroll
            for (int off = 16; off > 0; off >>= 1) v += __shfl_down(v, off, 32);
            if (tid == 0) atomicAdd(&accbuf[b*8 + 0], v);
        }
    } else if (h == 1) {
        if (tid < 128) {
            const int j = tid >> 5, s = tid & 31;
            float v = (s >= n0 && s < n0 + n1) ? X4[s*4 + j] : 0.f;
            #pragma unroll
            for (int off = 16; off > 0; off >>= 1) v += __shfl_down(v, off, 32);
            if (s == 0) atomicAdd(&accbuf[b*8 + 1 + j], v);
        }
    } else {
        if (tid < 96) {
            const int j = tid >> 5, s = tid & 31;
            float v = (s >= n0 && s < n0 + n1) ? X4[s*4 + j] : 0.f;
            #pragma unroll
            for (int off = 16; off > 0; off >>= 1) v += __shfl_down(v, off, 32);
            if (s == 0) atomicAdd(&accbuf[b*8 + 5 + j], v);
        }
    }
}

// ---------------- K5: valid mask + finalize reductions ----------------
__global__ __launch_bounds__(1024) void k_final(
    const int* __restrict__ np_, const float* __restrict__ acc, float* __restrict__ out)
{
    const int b = blockIdx.x, tid = threadIdx.x;
    const int n0 = np_[2*b], n1 = np_[2*b+1];
    const int t = tid >> 5, s = tid & 31;
    out[O_VALID + b*1024 + tid] = (t < n0 && s >= n0 && s < n0 + n1) ? 1.f : 0.f;
    const float pf = (float)(n0 * n1);
    if (tid == 0) {
        out[O_CAM + b] = 1.f / (1.f + expf(-acc[b*8] / pf));
    } else if (tid <= 4) {
        out[O_ROT + b*4 + (tid - 1)] = acc[b*8 + tid] / pf;
    } else if (tid <= 7) {
        out[O_TRANS + b*3 + (tid - 5)] = acc[b*8 + tid] / pf;
    }
}

extern "C" void kernel_launch(void* const* d_in, const int* in_sizes, int n_in,
                              void* d_out, int out_size, void* d_ws, size_t ws_size,
                              hipStream_t stream) {
    (void)in_sizes; (void)n_in; (void)out_size; (void)ws_size;
    const float* emb = (const float*)d_in[0];
    const int*   np_ = (const int*)d_in[1];
    const float* w0  = (const float*)d_in[2];
    const float* b0  = (const float*)d_in[3];
    const float* w1  = (const float*)d_in[4];
    const float* b1  = (const float*)d_in[5];
    const float* w2  = (const float*)d_in[6];
    const float* b2  = (const float*)d_in[7];
    const float* w3  = (const float*)d_in[8];
    const float* b3  = (const float*)d_in[9];
    const float* w4  = (const float*)d_in[10];
    const float* b4  = (const float*)d_in[11];

    float* ws  = (float*)d_ws;
    float* out = (float*)d_out;
    ushort_t* bt = (ushort_t*)(ws + OFF_BT);

    hipMemsetAsync(ws + OFF_ACC, 0, 512 * sizeof(float), stream);

    k_groups<<<64, 256, 0, stream>>>(emb, np_, ws + OFF_G1, ws + OFF_G2);
    k_AC<<<dim3(2, 64, 8), 256, 0, stream>>>(emb, w0, ws + OFF_A, ws + OFF_C);
    k_G<<<dim3(2, 64, 4), 256, 0, stream>>>(ws + OFF_G1, ws + OFF_G2, w0, b0, ws + OFF_G);
    k_wprep<<<1344, 64, 0, stream>>>(w1, w2, w3, bt);
    k_main<<<dim3(32, 64, 4), 256, 0, stream>>>(
        ws + OFF_A, ws + OFF_C, ws + OFF_G, bt,
        b1, b2, b3, w4, b4, np_, out, ws + OFF_ACC);
    k_final<<<64, 1024, 0, stream>>>(np_, ws + OFF_ACC, out);
}

// Round 3
// 135.611 us; speedup vs baseline: 7.7729x; 2.0242x over previous
//
#include <hip/hip_runtime.h>

typedef float f32x4 __attribute__((ext_vector_type(4)));
typedef short short8 __attribute__((ext_vector_type(8)));
typedef unsigned short ushort_t;
typedef unsigned int uint_t;

// (B,T,D,H) = (64, 32, 256, 4); DIMS = [1024, 512, 256, 128, 64, 4]
constexpr int O_CAM   = 0;
constexpr int O_ROT   = 64;
constexpr int O_TRANS = 320;
constexpr int O_PLANE = 512;
constexpr int O_VALID = 66048;

// Workspace layout (byte offsets)
constexpr size_t B_G1  = 0;         // f32 [64][256]
constexpr size_t B_G2  = 65536;     // f32 [64][256]
constexpr size_t B_G   = 131072;    // f32 [4][64][512]
constexpr size_t B_ACC = 655360;    // f32 [64][8]
constexpr size_t B_ABF = 657408;    // bf16 [4][64][32][512]  (A' = A + G)
constexpr size_t B_CBF = 9046016;   // bf16 [4][64][32][512]
constexpr size_t B_BT1 = 17434624;  // bf16 frag [4][16][16][64][8]
constexpr size_t B_BT2 = 18483200;  // bf16 frag [4][8][8][64][8]
constexpr size_t B_BT3 = 18745344;  // bf16 frag [4][4][4][64][8]
constexpr size_t B_BT0 = 18810880;  // bf16 frag [4*2][8][32][64][8]  (W0 a|c slices)
// end = 20908032 bytes (~21 MB)

__device__ __forceinline__ ushort_t f2bf(float f) {
    uint_t u = __float_as_uint(f);
    return (ushort_t)((u + 0x7FFFu + ((u >> 16) & 1u)) >> 16);
}

// ---------------- K1: group means g1, g2 ----------------
__global__ __launch_bounds__(256) void k_groups(
    const float* __restrict__ emb, const int* __restrict__ np_,
    float* __restrict__ g1, float* __restrict__ g2)
{
    const int b = blockIdx.x, d = threadIdx.x;
    const int n0 = np_[2*b], n1 = np_[2*b+1];
    const float* e = emb + (size_t)b*32*256 + d;
    float a1 = 0.f, a2 = 0.f;
    for (int t = 0; t < 32; ++t) {
        float v = e[(size_t)t*256];
        if (t < n0) a1 += v;
        else if (t < n0 + n1) a2 += v;
    }
    g1[b*256 + d] = a1 / n0;
    g2[b*256 + d] = a2 / n1;
}

// ---------------- K2: G = g1*W0c + g2*W0d + b0 (f32) ----------------
__global__ __launch_bounds__(256) void k_G(
    const float* __restrict__ g1, const float* __restrict__ g2,
    const float* __restrict__ w0, const float* __restrict__ b0,
    float* __restrict__ Gbuf)
{
    const int half = blockIdx.x, b = blockIdx.y, h = blockIdx.z;
    const int tid = threadIdx.x;
    __shared__ float s1[256], s2[256];
    s1[tid] = g1[b*256 + tid];
    s2[tid] = g2[b*256 + tid];
    __syncthreads();

    const int k = half*256 + tid;
    const float* wA = w0 + (size_t)h*(1024*512) + (size_t)512*512 + k;
    const float* wB = wA + (size_t)256*512;
    float a = b0[h*512 + k];
    for (int d = 0; d < 256; ++d) {
        a = fmaf(s1[d], wA[(size_t)d*512], a);
        a = fmaf(s2[d], wB[(size_t)d*512], a);
    }
    Gbuf[(size_t)(h*64 + b)*512 + k] = a;
}

// ---------------- K-prep: fragment-linear bf16 weights (layers 1-3) ----------------
// frag: lane l elem j = W[h][d = ks*32 + (l>>4)*8 + j][n = nt*16 + (l&15)]
__global__ __launch_bounds__(64) void k_wprep(
    const float* __restrict__ w1, const float* __restrict__ w2, const float* __restrict__ w3,
    ushort_t* __restrict__ bt1, ushort_t* __restrict__ bt2, ushort_t* __restrict__ bt3)
{
    int c = blockIdx.x;
    const float* w; ushort_t* dst; int K, N;
    if (c < 1024)      {           w = w1; dst = bt1 + (size_t)c*512; K = 512; N = 256; }
    else if (c < 1280) { c -= 1024; w = w2; dst = bt2 + (size_t)c*512; K = 256; N = 128; }
    else               { c -= 1280; w = w3; dst = bt3 + (size_t)c*512; K = 128; N = 64;  }
    const int NT = N/16, KS_NT = (K/32)*NT;
    const int h = c / KS_NT, rem = c % KS_NT, ks = rem / NT, nt = rem % NT;
    const int l = threadIdx.x;
    const int n = nt*16 + (l & 15);
    const int d0 = ks*32 + ((l >> 4) << 3);
    short8 o;
    #pragma unroll
    for (int j = 0; j < 8; ++j)
        o[j] = (short)f2bf(w[((size_t)(h*K + d0 + j))*N + n]);
    *(short8*)(dst + (size_t)l*8) = o;
}

// ---------------- K-prep0: W0 a/c-slice fragments ----------------
// c = ((h*2+isC)*8 + ks)*32 + nt
__global__ __launch_bounds__(64) void k_wprep0(
    const float* __restrict__ w0, ushort_t* __restrict__ bt0)
{
    const int c = blockIdx.x;
    const int nt = c & 31, ks = (c >> 5) & 7, hc = c >> 8;
    const int h = hc >> 1, isC = hc & 1;
    const int l = threadIdx.x;
    const int n = nt*16 + (l & 15);
    const int d0 = isC*256 + ks*32 + ((l >> 4) << 3);
    short8 o;
    #pragma unroll
    for (int j = 0; j < 8; ++j)
        o[j] = (short)f2bf(w0[((size_t)h*1024 + d0 + j)*512 + n]);
    *(short8*)(bt0 + ((size_t)c*64 + l)*8) = o;
}

// ---------------- K3: A' and C via MFMA (M=32, K=256, N=512) ----------------
// grid (64 b, 8 hc); hc = h*2 + isC. A' = emb@W0a + G ; C = emb@W0c. bf16 out.
__global__ __launch_bounds__(256) void k_AC(
    const float* __restrict__ emb, const ushort_t* __restrict__ bt0,
    const float* __restrict__ Gbuf,
    ushort_t* __restrict__ Abf, ushort_t* __restrict__ Cbf)
{
    const int b = blockIdx.x, hc = blockIdx.y;
    const int h = hc >> 1, isC = hc & 1;
    const int tid = threadIdx.x;
    const int l = tid & 63, w4 = tid >> 6;
    const int lrow = l & 15, lko = l >> 4;

    __shared__ __align__(16) char es[16384];   // bf16 [32][256], rowstride 512B, swizzled

    // stage emb -> bf16 LDS
    {
        const float* eb = emb + (size_t)b*8192;
        #pragma unroll
        for (int j = 0; j < 16; ++j) {
            const int flat = j*256 + tid;          // u32 index
            const int row = flat >> 7, cp = flat & 127;
            const float2 v = *(const float2*)(eb + row*256 + cp*2);
            const uint_t p = (uint_t)f2bf(v.x) | ((uint_t)f2bf(v.y) << 16);
            const int byte = (row*512 + cp*4) ^ ((row & 7) << 4);
            *(uint_t*)(es + byte) = p;
        }
    }
    __syncthreads();

    f32x4 acc[2][8];
    #pragma unroll
    for (int mt = 0; mt < 2; ++mt)
        #pragma unroll
        for (int nt = 0; nt < 8; ++nt) acc[mt][nt] = (f32x4){0.f,0.f,0.f,0.f};

    const ushort_t* bp = bt0 + (size_t)hc*131072 + (size_t)(w4*8)*512 + (size_t)l*8;
    short8 bb[2][8];
    #pragma unroll
    for (int nt = 0; nt < 8; ++nt) bb[0][nt] = *(const short8*)(bp + nt*512);
    #pragma unroll
    for (int ks = 0; ks < 8; ++ks) {
        if (ks < 7) {
            #pragma unroll
            for (int nt = 0; nt < 8; ++nt)
                bb[(ks+1)&1][nt] = *(const short8*)(bp + (size_t)(ks+1)*16384 + nt*512);
        }
        const int o = (lrow*512 + ks*64 + lko*16) ^ ((lrow & 7) << 4);
        const short8 a0 = *(const short8*)(es + o);
        const short8 a1 = *(const short8*)(es + o + 8192);
        #pragma unroll
        for (int nt = 0; nt < 8; ++nt) {
            acc[0][nt] = __builtin_amdgcn_mfma_f32_16x16x32_bf16(a0, bb[ks&1][nt], acc[0][nt], 0, 0, 0);
            acc[1][nt] = __builtin_amdgcn_mfma_f32_16x16x32_bf16(a1, bb[ks&1][nt], acc[1][nt], 0, 0, 0);
        }
    }

    ushort_t* dst = (isC ? Cbf : Abf) + (size_t)(h*64 + b)*32*512;
    const float* Gr = Gbuf + (size_t)(h*64 + b)*512;
    #pragma unroll
    for (int nt = 0; nt < 8; ++nt) {
        const int col = (w4*8 + nt)*16 + lrow;
        const float g = isC ? 0.f : Gr[col];
        #pragma unroll
        for (int mt = 0; mt < 2; ++mt)
            #pragma unroll
            for (int r = 0; r < 4; ++r) {
                const int row = mt*16 + lko*4 + r;
                dst[row*512 + col] = f2bf(acc[mt][nt][r] + g);
            }
    }
}

// ---------------- K4a: h=3 fused MLP per (t, b), M=32 ----------------
__global__ __launch_bounds__(256) void k_main3(
    const ushort_t* __restrict__ Abf, const ushort_t* __restrict__ Cbf,
    const ushort_t* __restrict__ bt1, const ushort_t* __restrict__ bt2, const ushort_t* __restrict__ bt3,
    const float* __restrict__ b1, const float* __restrict__ b2, const float* __restrict__ b3,
    const float* __restrict__ w4, const float* __restrict__ b4,
    float* __restrict__ out)
{
    const int t = blockIdx.x, b = blockIdx.y;
    const int h = 3;
    const int tid = threadIdx.x;
    const int l = tid & 63, w = tid >> 6;
    const int lrow = l & 15, lko = l >> 4;
    const size_t hb = (size_t)(h*64 + b);

    __shared__ __align__(16) char smem[49152];

    // ---- X0 = relu(A'[t] + C[s]) bf16 [32][512], rowstride 1024B, swizzled ----
    {
        const uint_t pa = ((const uint_t*)(Abf + (hb*32 + t)*512))[tid];
        const float alo = __uint_as_float(pa << 16);
        const float ahi = __uint_as_float(pa & 0xffff0000u);
        const uint_t* Crow = (const uint_t*)(Cbf + (hb*32)*512) + tid;
        for (int s = 0; s < 32; ++s) {
            const uint_t pc = Crow[s*256];
            const float xlo = fmaxf(alo + __uint_as_float(pc << 16), 0.f);
            const float xhi = fmaxf(ahi + __uint_as_float(pc & 0xffff0000u), 0.f);
            const uint_t p = (uint_t)f2bf(xlo) | ((uint_t)f2bf(xhi) << 16);
            const int byte = (s*1024 + tid*4) ^ ((s & 7) << 4);
            *(uint_t*)(smem + byte) = p;
        }
    }
    __syncthreads();

    // ---- layer1: 512 -> 256 ----
    f32x4 acc1[2][4];
    #pragma unroll
    for (int mt = 0; mt < 2; ++mt)
        #pragma unroll
        for (int nt = 0; nt < 4; ++nt) acc1[mt][nt] = (f32x4){0.f,0.f,0.f,0.f};
    {
        const ushort_t* bp = bt1 + (size_t)h*131072 + (size_t)(w*4)*512 + (size_t)l*8;
        short8 bb[2][4];
        #pragma unroll
        for (int nt = 0; nt < 4; ++nt) bb[0][nt] = *(const short8*)(bp + nt*512);
        #pragma unroll
        for (int ks = 0; ks < 16; ++ks) {
            if (ks < 15) {
                #pragma unroll
                for (int nt = 0; nt < 4; ++nt)
                    bb[(ks+1)&1][nt] = *(const short8*)(bp + (size_t)(ks+1)*8192 + nt*512);
            }
            const int o = (lrow*1024 + ks*64 + lko*16) ^ ((lrow & 7) << 4);
            const short8 a0 = *(const short8*)(smem + o);
            const short8 a1 = *(const short8*)(smem + o + 16384);
            #pragma unroll
            for (int nt = 0; nt < 4; ++nt) {
                acc1[0][nt] = __builtin_amdgcn_mfma_f32_16x16x32_bf16(a0, bb[ks&1][nt], acc1[0][nt], 0, 0, 0);
                acc1[1][nt] = __builtin_amdgcn_mfma_f32_16x16x32_bf16(a1, bb[ks&1][nt], acc1[1][nt], 0, 0, 0);
            }
        }
    }
    char* X1 = smem + 32768;   // bf16 [32][256], rowstride 512B, swizzled
    #pragma unroll
    for (int nt = 0; nt < 4; ++nt) {
        const int col = w*64 + nt*16 + lrow;
        const float bias = b1[h*256 + col];
        #pragma unroll
        for (int mt = 0; mt < 2; ++mt)
            #pragma unroll
            for (int r = 0; r < 4; ++r) {
                const int row = mt*16 + lko*4 + r;
                const int byte = (row*512 + col*2) ^ ((row & 7) << 4);
                *(ushort_t*)(X1 + byte) = f2bf(fmaxf(acc1[mt][nt][r] + bias, 0.f));
            }
    }
    __syncthreads();

    // ---- layer2: 256 -> 128 (X2 overlays X0) ----
    f32x4 acc2[2][2];
    #pragma unroll
    for (int mt = 0; mt < 2; ++mt)
        #pragma unroll
        for (int nt = 0; nt < 2; ++nt) acc2[mt][nt] = (f32x4){0.f,0.f,0.f,0.f};
    {
        const ushort_t* bp = bt2 + (size_t)h*32768 + (size_t)(w*2)*512 + (size_t)l*8;
        short8 bb[2][2];
        #pragma unroll
        for (int nt = 0; nt < 2; ++nt) bb[0][nt] = *(const short8*)(bp + nt*512);
        #pragma unroll
        for (int ks = 0; ks < 8; ++ks) {
            if (ks < 7) {
                #pragma unroll
                for (int nt = 0; nt < 2; ++nt)
                    bb[(ks+1)&1][nt] = *(const short8*)(bp + (size_t)(ks+1)*4096 + nt*512);
            }
            const int o = (lrow*512 + ks*64 + lko*16) ^ ((lrow & 7) << 4);
            const short8 a0 = *(const short8*)(X1 + o);
            const short8 a1 = *(const short8*)(X1 + o + 8192);
            #pragma unroll
            for (int nt = 0; nt < 2; ++nt) {
                acc2[0][nt] = __builtin_amdgcn_mfma_f32_16x16x32_bf16(a0, bb[ks&1][nt], acc2[0][nt], 0, 0, 0);
                acc2[1][nt] = __builtin_amdgcn_mfma_f32_16x16x32_bf16(a1, bb[ks&1][nt], acc2[1][nt], 0, 0, 0);
            }
        }
    }
    char* X2 = smem;           // bf16 [32][128], rowstride 256B, swizzled
    #pragma unroll
    for (int nt = 0; nt < 2; ++nt) {
        const int col = w*32 + nt*16 + lrow;
        const float bias = b2[h*128 + col];
        #pragma unroll
        for (int mt = 0; mt < 2; ++mt)
            #pragma unroll
            for (int r = 0; r < 4; ++r) {
                const int row = mt*16 + lko*4 + r;
                const int byte = (row*256 + col*2) ^ ((row & 7) << 4);
                *(ushort_t*)(X2 + byte) = f2bf(fmaxf(acc2[mt][nt][r] + bias, 0.f));
            }
    }
    __syncthreads();

    // ---- layer3: 128 -> 64 ----
    f32x4 acc3[2];
    acc3[0] = (f32x4){0.f,0.f,0.f,0.f};
    acc3[1] = (f32x4){0.f,0.f,0.f,0.f};
    {
        const ushort_t* bp = bt3 + (size_t)h*8192 + (size_t)w*512 + (size_t)l*8;
        short8 bb[2];
        bb[0] = *(const short8*)(bp);
        #pragma unroll
        for (int ks = 0; ks < 4; ++ks) {
            if (ks < 3) bb[(ks+1)&1] = *(const short8*)(bp + (size_t)(ks+1)*2048);
            const int o = (lrow*256 + ks*64 + lko*16) ^ ((lrow & 7) << 4);
            const short8 a0 = *(const short8*)(X2 + o);
            const short8 a1 = *(const short8*)(X2 + o + 4096);
            acc3[0] = __builtin_amdgcn_mfma_f32_16x16x32_bf16(a0, bb[ks&1], acc3[0], 0, 0, 0);
            acc3[1] = __builtin_amdgcn_mfma_f32_16x16x32_bf16(a1, bb[ks&1], acc3[1], 0, 0, 0);
        }
    }
    float* X3 = (float*)(smem + 8192);   // f32 [32][64]
    {
        const int col = w*16 + lrow;
        const float bias = b3[h*64 + col];
        #pragma unroll
        for (int mt = 0; mt < 2; ++mt)
            #pragma unroll
            for (int r = 0; r < 4; ++r) {
                const int row = mt*16 + lko*4 + r;
                X3[row*64 + col] = fmaxf(acc3[mt][r] + bias, 0.f);
            }
    }
    __syncthreads();

    // ---- layer4: 64 -> 4 (only output 0 needed for h=3) ----
    float* X4 = (float*)(smem + 16384);  // f32 [32]
    if (tid < 32) {
        const float* wr = w4 + (size_t)h*256;
        float a = b4[h*4];
        const float* xr = X3 + tid*64;
        #pragma unroll
        for (int d = 0; d < 64; ++d) a = fmaf(xr[d], wr[(size_t)d*4], a);
        X4[tid] = a;
    }
    __syncthreads();

    if (tid < 32)
        out[O_PLANE + b*1024 + t*32 + tid] = 1.f / (1.f + expf(-X4[tid]));
}

// ---------------- K4b: h<3 fused MLP per (t, b, h), M=16 rows s=n0..n0+15 ----------------
__global__ __launch_bounds__(256) void k_main12(
    const ushort_t* __restrict__ Abf, const ushort_t* __restrict__ Cbf,
    const ushort_t* __restrict__ bt1, const ushort_t* __restrict__ bt2, const ushort_t* __restrict__ bt3,
    const float* __restrict__ b1, const float* __restrict__ b2, const float* __restrict__ b3,
    const float* __restrict__ w4, const float* __restrict__ b4,
    const int* __restrict__ np_, float* __restrict__ accbuf)
{
    const int t = blockIdx.x, b = blockIdx.y, h = blockIdx.z;
    const int n0 = np_[2*b], n1 = np_[2*b+1];
    if (t >= n0) return;

    const int tid = threadIdx.x;
    const int l = tid & 63, w = tid >> 6;
    const int lrow = l & 15, lko = l >> 4;
    const size_t hb = (size_t)(h*64 + b);

    __shared__ __align__(16) char smem[24832];
    // X0 [16][512] @0 (16KB); X1 [16][256] @16384 (8KB); X2 [16][128] @0 (4KB);
    // X3 f32 [16][64] @4096 (4KB); X4 f32 [16][4] @24576

    // ---- X0 = relu(A'[t] + C[n0+r]) ----
    {
        const uint_t pa = ((const uint_t*)(Abf + (hb*32 + t)*512))[tid];
        const float alo = __uint_as_float(pa << 16);
        const float ahi = __uint_as_float(pa & 0xffff0000u);
        const uint_t* Crow = (const uint_t*)(Cbf + (hb*32 + n0)*512) + tid;
        for (int r = 0; r < 16; ++r) {
            const uint_t pc = Crow[r*256];
            const float xlo = fmaxf(alo + __uint_as_float(pc << 16), 0.f);
            const float xhi = fmaxf(ahi + __uint_as_float(pc & 0xffff0000u), 0.f);
            const uint_t p = (uint_t)f2bf(xlo) | ((uint_t)f2bf(xhi) << 16);
            const int byte = (r*1024 + tid*4) ^ ((r & 7) << 4);
            *(uint_t*)(smem + byte) = p;
        }
    }
    __syncthreads();

    // ---- layer1 ----
    f32x4 acc1[4];
    #pragma unroll
    for (int nt = 0; nt < 4; ++nt) acc1[nt] = (f32x4){0.f,0.f,0.f,0.f};
    {
        const ushort_t* bp = bt1 + (size_t)h*131072 + (size_t)(w*4)*512 + (size_t)l*8;
        short8 bb[2][4];
        #pragma unroll
        for (int nt = 0; nt < 4; ++nt) bb[0][nt] = *(const short8*)(bp + nt*512);
        #pragma unroll
        for (int ks = 0; ks < 16; ++ks) {
            if (ks < 15) {
                #pragma unroll
                for (int nt = 0; nt < 4; ++nt)
                    bb[(ks+1)&1][nt] = *(const short8*)(bp + (size_t)(ks+1)*8192 + nt*512);
            }
            const int o = (lrow*1024 + ks*64 + lko*16) ^ ((lrow & 7) << 4);
            const short8 a0 = *(const short8*)(smem + o);
            #pragma unroll
            for (int nt = 0; nt < 4; ++nt)
                acc1[nt] = __builtin_amdgcn_mfma_f32_16x16x32_bf16(a0, bb[ks&1][nt], acc1[nt], 0, 0, 0);
        }
    }
    char* X1 = smem + 16384;
    #pragma unroll
    for (int nt = 0; nt < 4; ++nt) {
        const int col = w*64 + nt*16 + lrow;
        const float bias = b1[h*256 + col];
        #pragma unroll
        for (int r = 0; r < 4; ++r) {
            const int row = lko*4 + r;
            const int byte = (row*512 + col*2) ^ ((row & 7) << 4);
            *(ushort_t*)(X1 + byte) = f2bf(fmaxf(acc1[nt][r] + bias, 0.f));
        }
    }
    __syncthreads();

    // ---- layer2 ----
    f32x4 acc2[2];
    acc2[0] = (f32x4){0.f,0.f,0.f,0.f};
    acc2[1] = (f32x4){0.f,0.f,0.f,0.f};
    {
        const ushort_t* bp = bt2 + (size_t)h*32768 + (size_t)(w*2)*512 + (size_t)l*8;
        short8 bb[2][2];
        #pragma unroll
        for (int nt = 0; nt < 2; ++nt) bb[0][nt] = *(const short8*)(bp + nt*512);
        #pragma unroll
        for (int ks = 0; ks < 8; ++ks) {
            if (ks < 7) {
                #pragma unroll
                for (int nt = 0; nt < 2; ++nt)
                    bb[(ks+1)&1][nt] = *(const short8*)(bp + (size_t)(ks+1)*4096 + nt*512);
            }
            const int o = (lrow*512 + ks*64 + lko*16) ^ ((lrow & 7) << 4);
            const short8 a0 = *(const short8*)(X1 + o);
            #pragma unroll
            for (int nt = 0; nt < 2; ++nt)
                acc2[nt] = __builtin_amdgcn_mfma_f32_16x16x32_bf16(a0, bb[ks&1][nt], acc2[nt], 0, 0, 0);
        }
    }
    char* X2 = smem;
    #pragma unroll
    for (int nt = 0; nt < 2; ++nt) {
        const int col = w*32 + nt*16 + lrow;
        const float bias = b2[h*128 + col];
        #pragma unroll
        for (int r = 0; r < 4; ++r) {
            const int row = lko*4 + r;
            const int byte = (row*256 + col*2) ^ ((row & 7) << 4);
            *(ushort_t*)(X2 + byte) = f2bf(fmaxf(acc2[nt][r] + bias, 0.f));
        }
    }
    __syncthreads();

    // ---- layer3 ----
    f32x4 acc3 = (f32x4){0.f,0.f,0.f,0.f};
    {
        const ushort_t* bp = bt3 + (size_t)h*8192 + (size_t)w*512 + (size_t)l*8;
        short8 bb[2];
        bb[0] = *(const short8*)(bp);
        #pragma unroll
        for (int ks = 0; ks < 4; ++ks) {
            if (ks < 3) bb[(ks+1)&1] = *(const short8*)(bp + (size_t)(ks+1)*2048);
            const int o = (lrow*256 + ks*64 + lko*16) ^ ((lrow & 7) << 4);
            const short8 a0 = *(const short8*)(X2 + o);
            acc3 = __builtin_amdgcn_mfma_f32_16x16x32_bf16(a0, bb[ks&1], acc3, 0, 0, 0);
        }
    }
    float* X3 = (float*)(smem + 4096);
    {
        const int col = w*16 + lrow;
        const float bias = b3[h*64 + col];
        #pragma unroll
        for (int r = 0; r < 4; ++r)
            X3[(lko*4 + r)*64 + col] = fmaxf(acc3[r] + bias, 0.f);
    }
    __syncthreads();

    // ---- layer4 ----
    float* X4 = (float*)(smem + 24576);   // f32 [16][4]
    if (tid < 64) {
        const int r = tid >> 2, o = tid & 3;
        const float* wr = w4 + (size_t)h*256 + o;
        float a = b4[h*4 + o];
        const float* xr = X3 + r*64;
        #pragma unroll
        for (int d = 0; d < 64; ++d) a = fmaf(xr[d], wr[(size_t)d*4], a);
        X4[r*4 + o] = a;
    }
    __syncthreads();

    // ---- masked reductions (rows r valid iff r < n1) ----
    const int nj = (h == 0) ? 1 : ((h == 1) ? 4 : 3);
    if (tid < 16*nj) {
        const int j = tid >> 4, r = tid & 15;
        float v = (r < n1) ? X4[r*4 + j] : 0.f;
        #pragma unroll
        for (int off = 8; off > 0; off >>= 1) v += __shfl_down(v, off, 16);
        if (r == 0) {
            const int slot = (h == 0) ? 0 : ((h == 1) ? 1 + j : 5 + j);
            atomicAdd(&accbuf[b*8 + slot], v);
        }
    }
}

// ---------------- K5: valid mask + finalize reductions ----------------
__global__ __launch_bounds__(1024) void k_final(
    const int* __restrict__ np_, const float* __restrict__ acc, float* __restrict__ out)
{
    const int b = blockIdx.x, tid = threadIdx.x;
    const int n0 = np_[2*b], n1 = np_[2*b+1];
    const int t = tid >> 5, s = tid & 31;
    out[O_VALID + b*1024 + tid] = (t < n0 && s >= n0 && s < n0 + n1) ? 1.f : 0.f;
    const float pf = (float)(n0 * n1);
    if (tid == 0) {
        out[O_CAM + b] = 1.f / (1.f + expf(-acc[b*8] / pf));
    } else if (tid <= 4) {
        out[O_ROT + b*4 + (tid - 1)] = acc[b*8 + tid] / pf;
    } else if (tid <= 7) {
        out[O_TRANS + b*3 + (tid - 5)] = acc[b*8 + tid] / pf;
    }
}

extern "C" void kernel_launch(void* const* d_in, const int* in_sizes, int n_in,
                              void* d_out, int out_size, void* d_ws, size_t ws_size,
                              hipStream_t stream) {
    (void)in_sizes; (void)n_in; (void)out_size; (void)ws_size;
    const float* emb = (const float*)d_in[0];
    const int*   np_ = (const int*)d_in[1];
    const float* w0  = (const float*)d_in[2];
    const float* b0  = (const float*)d_in[3];
    const float* w1  = (const float*)d_in[4];
    const float* b1  = (const float*)d_in[5];
    const float* w2  = (const float*)d_in[6];
    const float* b2  = (const float*)d_in[7];
    const float* w3  = (const float*)d_in[8];
    const float* b3  = (const float*)d_in[9];
    const float* w4  = (const float*)d_in[10];
    const float* b4  = (const float*)d_in[11];

    char* W = (char*)d_ws;
    float* out = (float*)d_out;
    float*    g1  = (float*)(W + B_G1);
    float*    g2  = (float*)(W + B_G2);
    float*    G   = (float*)(W + B_G);
    float*    acc = (float*)(W + B_ACC);
    ushort_t* Abf = (ushort_t*)(W + B_ABF);
    ushort_t* Cbf = (ushort_t*)(W + B_CBF);
    ushort_t* bt1 = (ushort_t*)(W + B_BT1);
    ushort_t* bt2 = (ushort_t*)(W + B_BT2);
    ushort_t* bt3 = (ushort_t*)(W + B_BT3);
    ushort_t* bt0 = (ushort_t*)(W + B_BT0);

    hipMemsetAsync(acc, 0, 512 * sizeof(float), stream);

    k_groups<<<64, 256, 0, stream>>>(emb, np_, g1, g2);
    k_G<<<dim3(2, 64, 4), 256, 0, stream>>>(g1, g2, w0, b0, G);
    k_wprep<<<1344, 64, 0, stream>>>(w1, w2, w3, bt1, bt2, bt3);
    k_wprep0<<<2048, 64, 0, stream>>>(w0, bt0);
    k_AC<<<dim3(64, 8), 256, 0, stream>>>(emb, bt0, G, Abf, Cbf);
    k_main3<<<dim3(32, 64), 256, 0, stream>>>(Abf, Cbf, bt1, bt2, bt3,
                                              b1, b2, b3, w4, b4, out);
    k_main12<<<dim3(16, 64, 3), 256, 0, stream>>>(Abf, Cbf, bt1, bt2, bt3,
                                                  b1, b2, b3, w4, b4, np_, acc);
    k_final<<<64, 1024, 0, stream>>>(np_, acc, out);
}